// Round 14
// baseline (287.442 us; speedup 1.0000x reference)
//
#include <hip/hip_runtime.h>
#include <hip/hip_bf16.h>
#include <math.h>

typedef __hip_bfloat16 bf16;
typedef unsigned short u16;
typedef __attribute__((ext_vector_type(8))) short bf16x8;
typedef __attribute__((ext_vector_type(4))) float f32x4;
typedef __attribute__((ext_vector_type(16))) float f32x16;
typedef __attribute__((ext_vector_type(4))) unsigned u32x4;

__device__ __forceinline__ float us2f(u16 u) { return __uint_as_float(((unsigned)u) << 16); }
__device__ __forceinline__ u16 f2us(float f) { bf16 h = __float2bfloat16(f); return *(u16*)&h; }

__device__ __forceinline__ float wave_bcast_sum(float v) {
#pragma unroll
    for (int off = 32; off > 0; off >>= 1) v += __shfl_down(v, off);
    return __shfl(v, 0);
}

// async global->LDS, 16B per lane. LDS dest is wave-uniform base (+lane*16 by HW).
__device__ __forceinline__ void glds16(const u16* g, u16* l) {
    __builtin_amdgcn_global_load_lds((const __attribute__((address_space(1))) void*)g,
                                     (__attribute__((address_space(3))) void*)l, 16, 0, 0);
}

// ---------------------------------------------------------------------------
// Merged prep: qkv_w -> bf16, proj_w -> bf16, bias table in MFMA-FRAGMENT
// order: biasF[((h*11+tile)*11+chunk)*1024 + lane*16 + g*4 + q] =
// rpb[relidx(n,m)]/scale for n = tile*32 + (lane&31), m = chunk*32 +
// 4*(lane>>5) + 8*g + q; pads = 0.
// ---------------------------------------------------------------------------
__global__ __launch_bounds__(256) void k_prep(
    const float* __restrict__ qkv_w, const float* __restrict__ proj_w,
    const float* __restrict__ rpb,
    u16* __restrict__ qkv_wb, u16* __restrict__ proj_wb, float* __restrict__ biasF)
{
    int idx = blockIdx.x * 256 + threadIdx.x;
    if (idx < 110592) { qkv_wb[idx] = f2us(qkv_w[idx]); return; }
    idx -= 110592;
    if (idx < 36864) { proj_wb[idx] = f2us(proj_w[idx]); return; }
    idx -= 36864;
    if (idx >= 6 * 11 * 11 * 1024) return;
    int r16 = idx & 15;                    // g*4 + q
    int lane = (idx >> 4) & 63;
    int cell = idx >> 10;                  // (h*11 + tile)*11 + chunk
    int chunk = cell % 11;
    int t2 = cell / 11;
    int tile = t2 % 11;
    int h = t2 / 11;
    int g = r16 >> 2, q = r16 & 3;
    int hi = lane >> 5, l31 = lane & 31;
    int n = tile * 32 + l31;
    int m = chunk * 32 + 4 * hi + 8 * g + q;
    float v = 0.0f;
    if (m < 343 && n < 343) {
        int ni = n / 49, nr = n - ni * 49, nj = nr / 7, nk = nr - nj * 7;
        int mi = m / 49, mr = m - mi * 49, mj = mr / 7, mk = mr - mj * 7;
        int d = (ni - mi) * 169 + (nj - mj) * 13 + (nk - mk) + 1098;
        v = rpb[d * 6 + h] * 5.656854249492381f;   // * sqrt(32) = / scale
    }
    biasF[idx] = v;
}

// fc1_w + fc2_w -> bf16 (must run after attn frees the qkvb tail)
__global__ __launch_bounds__(256) void k_f2b2(
    const float* __restrict__ fc1_w, const float* __restrict__ fc2_w,
    u16* __restrict__ fc1_wb, u16* __restrict__ fc2_wb)
{
    int idx = blockIdx.x * 256 + threadIdx.x;
    if (idx < 147456) fc1_wb[idx] = f2us(fc1_w[idx]);
    else fc2_wb[idx - 147456] = f2us(fc2_w[idx - 147456]);
}

// ---------------------------------------------------------------------------
// LN1 + roll(-3,-3,-3) + window partition. f32 in -> bf16 out (window order).
// ---------------------------------------------------------------------------
__global__ __launch_bounds__(256) void k_ln1_winpart(
    const float* __restrict__ x, const float* __restrict__ g, const float* __restrict__ b,
    u16* __restrict__ out)
{
    int lane = threadIdx.x & 63;
    int t = blockIdx.x * 4 + (threadIdx.x >> 6);
    int bidx = t / (64 * 343);
    int r = t - bidx * (64 * 343);
    int w = r / 343;
    int n = r - w * 343;
    int wd = w >> 4, wh = (w >> 2) & 3, ww = w & 3;
    int i = n / 49, rem = n - i * 49;
    int j = rem / 7, k = rem - j * 7;
    int sd = wd * 7 + i + 3; if (sd >= 28) sd -= 28;
    int sh = wh * 7 + j + 3; if (sh >= 28) sh -= 28;
    int sw = ww * 7 + k + 3; if (sw >= 28) sw -= 28;
    size_t src = ((((size_t)bidx * 28 + sd) * 28 + sh) * 28 + sw) * 192;
    float v0 = x[src + lane], v1 = x[src + lane + 64], v2 = x[src + lane + 128];
    float s  = wave_bcast_sum(v0 + v1 + v2);
    float mu = s * (1.0f / 192.0f);
    float s2 = wave_bcast_sum(v0 * v0 + v1 * v1 + v2 * v2);
    float rs = rsqrtf(s2 * (1.0f / 192.0f) - mu * mu + 1e-5f);
    u16* op = out + (size_t)t * 192;
    op[lane]       = f2us((v0 - mu) * rs * g[lane]       + b[lane]);
    op[lane + 64]  = f2us((v1 - mu) * rs * g[lane + 64]  + b[lane + 64]);
    op[lane + 128] = f2us((v2 - mu) * rs * g[lane + 128] + b[lane + 128]);
}

// ---------------------------------------------------------------------------
// Fused: window reverse + roll(+3) + residual add (f32 x1 out) + LN2 (bf16 out)
// ---------------------------------------------------------------------------
__global__ __launch_bounds__(256) void k_add_winrev_ln2(
    const float* __restrict__ x, const u16* __restrict__ projw,
    const float* __restrict__ g, const float* __restrict__ b,
    float* __restrict__ x1, u16* __restrict__ h2)
{
    int lane = threadIdx.x & 63;
    int t = blockIdx.x * 4 + (threadIdx.x >> 6);
    int sw_ = t % 28, t1 = t / 28;
    int sh_ = t1 % 28, t2 = t1 / 28;
    int sd_ = t2 % 28, bidx = t2 / 28;
    int rd = sd_ + 25; if (rd >= 28) rd -= 28;   // (d-3) mod 28
    int rh = sh_ + 25; if (rh >= 28) rh -= 28;
    int rw = sw_ + 25; if (rw >= 28) rw -= 28;
    int wd = rd / 7, i = rd - wd * 7;
    int wh = rh / 7, j = rh - wh * 7;
    int ww = rw / 7, k = rw - ww * 7;
    int w = (wd << 4) + (wh << 2) + ww;
    int n = (i * 7 + j) * 7 + k;
    size_t src = (((size_t)(bidx * 64 + w)) * 343 + n) * 192;
    const float* xp = x + (size_t)t * 192;
    float v0 = xp[lane]       + us2f(projw[src + lane]);
    float v1 = xp[lane + 64]  + us2f(projw[src + lane + 64]);
    float v2 = xp[lane + 128] + us2f(projw[src + lane + 128]);
    float* op = x1 + (size_t)t * 192;
    op[lane] = v0; op[lane + 64] = v1; op[lane + 128] = v2;
    float s  = wave_bcast_sum(v0 + v1 + v2);
    float mu = s * (1.0f / 192.0f);
    float s2 = wave_bcast_sum(v0 * v0 + v1 * v1 + v2 * v2);
    float rs = rsqrtf(s2 * (1.0f / 192.0f) - mu * mu + 1e-5f);
    u16* hp = h2 + (size_t)t * 192;
    hp[lane]       = f2us((v0 - mu) * rs * g[lane]       + b[lane]);
    hp[lane + 64]  = f2us((v1 - mu) * rs * g[lane + 64]  + b[lane + 64]);
    hp[lane + 128] = f2us((v2 - mu) * rs * g[lane + 128] + b[lane + 128]);
}

// ---------------------------------------------------------------------------
// MFMA GEMM, BK=32 double-buffered 2-phase, XOR-swizzled LDS (4 slots/row:
// slot ^= row&3, both-sides). LDS 24.5KB -> 6 blocks/CU (2x the BK=64
// version): occupancy-end of the barrier/occupancy trade for short-K GEMMs.
// 1D grid + XCD-aware bijective block swizzle, y-major. BM=128, BN=64.
// K % 32 == 0. ACT: 0 none, 1 gelu. OUT: 1 bf16, 2 f32 + resid add.
// ---------------------------------------------------------------------------
template<int ACT, int OUT, int GX>
__global__ __launch_bounds__(256) void k_gemm32(
    const u16* __restrict__ A, const u16* __restrict__ W, const float* __restrict__ bias,
    u16* __restrict__ outB, float* __restrict__ outF, const float* __restrict__ resid,
    int M, int Nc, int K)
{
    __shared__ __align__(16) u16 As[2][128 * 32];
    __shared__ __align__(16) u16 Bs[2][64 * 32];
    int tid = threadIdx.x;
    int lane = tid & 63, wv = tid >> 6;
    int quad = lane >> 4, l16 = lane & 15;

    int nwg = gridDim.x, orig = blockIdx.x;
    int q = nwg >> 3, r = nwg & 7;
    int xcd = orig & 7, lin = orig >> 3;
    int L = (xcd < r ? xcd * (q + 1) : r * (q + 1) + (xcd - r) * q) + lin;
    int bx = L % GX, by = L / GX;
    int m0 = by << 7, n0 = bx << 6;

    f32x4 acc[2][4] = {};

    // staging: one glds16 per wave covers 16 rows x 32 cols. lane>>2 = row
    // in group, lane&3 = 8-u16 col slot; source col pre-swizzled by row&3.
    int srow = wv * 16 + (lane >> 2);
    int swz  = ((lane & 3) << 3) ^ (((lane >> 2) & 3) << 3);
    const u16* gA = A + (size_t)(m0 + srow) * K + swz;
    const u16* gB = W + (size_t)(n0 + srow) * K + swz;
    int rsA = 64 * K;                             // row step per i (64 rows)

    int nst = K >> 5;
#define STAGE32(buf, k0)                                                      \
    {                                                                         \
        glds16(gA + (k0),                &As[buf][(wv) * 512]);               \
        glds16(gA + (size_t)rsA + (k0),  &As[buf][(4 + wv) * 512]);           \
        glds16(gB + (k0),                &Bs[buf][(wv) * 512]);               \
    }

    STAGE32(0, 0);
    asm volatile("s_waitcnt vmcnt(0)" ::: "memory");
    __builtin_amdgcn_s_barrier();

    int rswz = (l16 & 3) << 3;                    // read-side swizzle (row&3 == l16&3)
    int cur = 0;
    for (int t = 0; t < nst; ++t) {
        if (t + 1 < nst) STAGE32(cur ^ 1, (t + 1) << 5);
        int ko = (quad * 8) ^ rswz;
        bf16x8 af[2], bfr[4];
#pragma unroll
        for (int mt = 0; mt < 2; mt++)
            af[mt] = *(const bf16x8*)&As[cur][(wv * 32 + mt * 16 + l16) * 32 + ko];
#pragma unroll
        for (int nt = 0; nt < 4; nt++)
            bfr[nt] = *(const bf16x8*)&Bs[cur][(nt * 16 + l16) * 32 + ko];
#pragma unroll
        for (int mt = 0; mt < 2; mt++)
#pragma unroll
            for (int nt = 0; nt < 4; nt++)
                acc[mt][nt] = __builtin_amdgcn_mfma_f32_16x16x32_bf16(af[mt], bfr[nt], acc[mt][nt], 0, 0, 0);
        asm volatile("s_waitcnt vmcnt(0)" ::: "memory");
        __builtin_amdgcn_s_barrier();
        cur ^= 1;
    }
#undef STAGE32
#pragma unroll
    for (int mt = 0; mt < 2; mt++) {
#pragma unroll
        for (int nt = 0; nt < 4; nt++) {
#pragma unroll
            for (int r2 = 0; r2 < 4; r2++) {
                int m = m0 + wv * 32 + mt * 16 + quad * 4 + r2;
                int n = n0 + nt * 16 + l16;
                float v = acc[mt][nt][r2] + bias[n];
                if (ACT == 1) v = 0.5f * v * (1.0f + erff(v * 0.70710678118654752f));
                size_t off = (size_t)m * Nc + n;
                if (OUT == 1) outB[off] = f2us(v);
                else outF[off] = resid[off] + v;
            }
        }
    }
}

// ---------------------------------------------------------------------------
// MFMA GEMM, BK=64 double-buffered 2-phase, XOR-swizzled LDS (kept for K=768).
// ---------------------------------------------------------------------------
template<int ACT, int OUT, int GX>
__global__ __launch_bounds__(256) void k_gemm_mfma(
    const u16* __restrict__ A, const u16* __restrict__ W, const float* __restrict__ bias,
    u16* __restrict__ outB, float* __restrict__ outF, const float* __restrict__ resid,
    int M, int Nc, int K)
{
    __shared__ __align__(16) u16 As[2][128 * 64];
    __shared__ __align__(16) u16 Bs[2][64 * 64];
    int tid = threadIdx.x;
    int lane = tid & 63, wv = tid >> 6;
    int quad = lane >> 4, l16 = lane & 15;

    int nwg = gridDim.x, orig = blockIdx.x;
    int q = nwg >> 3, r = nwg & 7;
    int xcd = orig & 7, lin = orig >> 3;
    int L = (xcd < r ? xcd * (q + 1) : r * (q + 1) + (xcd - r) * q) + lin;
    int bx = L % GX, by = L / GX;
    int m0 = by << 7, n0 = bx << 6;

    f32x4 acc[2][4] = {};

    int srow = wv * 8 + (lane >> 3);              // row for i=0
    int swz  = ((lane & 7) << 3) ^ (((lane >> 3) & 7) << 3);
    const u16* gA = A + (size_t)(m0 + srow) * K + swz;
    const u16* gB = W + (size_t)(n0 + srow) * K + swz;
    int rsA = 32 * K;                             // row step per iter (i*32 rows)

    int nst = K >> 6;
#define STAGE(buf, k0)                                                        \
    {                                                                         \
        _Pragma("unroll")                                                     \
        for (int i = 0; i < 4; i++)                                           \
            glds16(gA + (size_t)i * rsA + (k0), &As[buf][(i * 4 + wv) * 512]); \
        _Pragma("unroll")                                                     \
        for (int i = 0; i < 2; i++)                                           \
            glds16(gB + (size_t)i * rsA + (k0), &Bs[buf][(i * 4 + wv) * 512]); \
    }

    STAGE(0, 0);
    asm volatile("s_waitcnt vmcnt(0)" ::: "memory");
    __builtin_amdgcn_s_barrier();

    int rswz = (l16 & 7) << 3;                    // read-side swizzle (row&7 == l16&7)
    int cur = 0;
    for (int t = 0; t < nst; ++t) {
        if (t + 1 < nst) STAGE(cur ^ 1, (t + 1) << 6);
#pragma unroll
        for (int kk = 0; kk < 2; kk++) {
            int ko = (kk * 32 + quad * 8) ^ rswz;
            bf16x8 af[2], bfr[4];
#pragma unroll
            for (int mt = 0; mt < 2; mt++)
                af[mt] = *(const bf16x8*)&As[cur][(wv * 32 + mt * 16 + l16) * 64 + ko];
#pragma unroll
            for (int nt = 0; nt < 4; nt++)
                bfr[nt] = *(const bf16x8*)&Bs[cur][(nt * 16 + l16) * 64 + ko];
#pragma unroll
            for (int mt = 0; mt < 2; mt++)
#pragma unroll
                for (int nt = 0; nt < 4; nt++)
                    acc[mt][nt] = __builtin_amdgcn_mfma_f32_16x16x32_bf16(af[mt], bfr[nt], acc[mt][nt], 0, 0, 0);
        }
        asm volatile("s_waitcnt vmcnt(0)" ::: "memory");
        __builtin_amdgcn_s_barrier();
        cur ^= 1;
    }
#undef STAGE
#pragma unroll
    for (int mt = 0; mt < 2; mt++) {
#pragma unroll
        for (int nt = 0; nt < 4; nt++) {
#pragma unroll
            for (int r2 = 0; r2 < 4; r2++) {
                int m = m0 + wv * 32 + mt * 16 + quad * 4 + r2;
                int n = n0 + nt * 16 + l16;
                float v = acc[mt][nt][r2] + bias[n];
                if (ACT == 1) v = 0.5f * v * (1.0f + erff(v * 0.70710678118654752f));
                size_t off = (size_t)m * Nc + n;
                if (OUT == 1) outB[off] = f2us(v);
                else outF[off] = resid[off] + v;
            }
        }
    }
}

// ---------------------------------------------------------------------------
// Fused windowed attention (R8-proven): 32x32x16 MFMA, swapped QK^T,
// fragment-ordered bias C-in. 11 waves (704 thr), one query-tile per wave.
// ---------------------------------------------------------------------------
__global__ __launch_bounds__(704, 6) void k_attn(
    const u16* __restrict__ qkv, const float* __restrict__ biasF, u16* __restrict__ o_win)
{
    int head = blockIdx.x;
    int w = blockIdx.y;
    int bidx = blockIdx.z;
    __shared__ __align__(16) u16 Ks[352 * 40];
    __shared__ __align__(16) u16 Vt[32 * 360];
    __shared__ unsigned char lab[352];
    int tid = threadIdx.x;
    int lane = tid & 63, wv = tid >> 6;        // wv 0..10
    int hi = lane >> 5, l31 = lane & 31;
    size_t base = ((size_t)(bidx * 64 + w)) * 343;

    for (int i = tid; i < 2816; i += 704) {
        int m = i >> 3;
        int d4 = (i & 7) << 2;
        ushort4 kv = {0, 0, 0, 0}, vv = {0, 0, 0, 0};
        if (m < 343) {
            size_t off = (base + m) * 576 + head * 32 + d4;
            kv = *(const ushort4*)(qkv + off + 192);
            vv = *(const ushort4*)(qkv + off + 384);
        }
        *(ushort4*)&Ks[m * 40 + d4] = kv;
        Vt[(d4 + 0) * 360 + m] = vv.x;
        Vt[(d4 + 1) * 360 + m] = vv.y;
        Vt[(d4 + 2) * 360 + m] = vv.z;
        Vt[(d4 + 3) * 360 + m] = vv.w;
    }
    int wd = w >> 4, wh = (w >> 2) & 3, ww = w & 3;
    bool uni = (wd < 3) && (wh < 3) && (ww < 3);
    for (int n = tid; n < 352; n += 704) {
        unsigned char lv = 255;                      // pad rows never match
        if (n < 343) {
            int i = n / 49, rem = n - i * 49;
            int j = rem / 7, k = rem - j * 7;
            int gd = wd * 7 + i, gh = wh * 7 + j, gw = ww * 7 + k;
            int ld_ = (gd < 21) ? 0 : ((gd < 25) ? 1 : 2);
            int lh_ = (gh < 21) ? 0 : ((gh < 25) ? 1 : 2);
            int lw_ = (gw < 21) ? 0 : ((gw < 25) ? 1 : 2);
            lv = (unsigned char)(ld_ * 9 + lh_ * 3 + lw_);
        }
        lab[n] = lv;
    }
    __syncthreads();

    const float SCALE = 0.17677669529663687f;  // 1/sqrt(32)
    const f32x16 z16 = {0,0,0,0,0,0,0,0,0,0,0,0,0,0,0,0};

    int tile = wv;                              // one tile per wave, 0..10
    int n0 = tile * 32;
    int nq = n0 + l31; if (nq > 342) nq = 342;
    const u16* qp = qkv + (base + nq) * 576 + head * 32;
    bf16x8 bq0 = *(const bf16x8*)(qp + hi * 8);        // Q[n=l31][d=hi*8+j]
    bf16x8 bq1 = *(const bf16x8*)(qp + 16 + hi * 8);   // d=16+hi*8+j
    unsigned lr = lab[n0 + l31];
    const float* bfr = biasF + ((size_t)(head * 11 + tile) * 11) * 1024 + lane * 16;

    f32x16 o = z16;
    float psum = 0.0f;

    // mode: 0 = no mask, 1 = pad-kill only, 2 = full label mask
    auto chunk = [&](int c, int mode) {
        int mb = c * 32;
        const u16* kp = &Ks[(mb + l31) * 40 + hi * 8];
        bf16x8 ka0 = *(const bf16x8*)kp;
        bf16x8 ka1 = *(const bf16x8*)(kp + 16);
        f32x16 s;
        const float* bc = bfr + c * 1024;
#pragma unroll
        for (int g = 0; g < 4; ++g)
            ((float4*)&s)[g] = *(const float4*)(bc + g * 4);
        s = __builtin_amdgcn_mfma_f32_32x32x16_bf16(ka0, bq0, s, 0, 0, 0);
        s = __builtin_amdgcn_mfma_f32_32x32x16_bf16(ka1, bq1, s, 0, 0, 0);
        float p[16];
        if (mode == 0) {
#pragma unroll
            for (int r = 0; r < 16; ++r) p[r] = __expf(s[r] * SCALE);
        } else if (mode == 1) {
#pragma unroll
            for (int r = 0; r < 16; ++r) {
                int m = mb + 4 * hi + 8 * (r >> 2) + (r & 3);
                float e = __expf(s[r] * SCALE);
                p[r] = (m < 343) ? e : 0.0f;
            }
        } else {
            unsigned labw[4];
#pragma unroll
            for (int g = 0; g < 4; ++g)
                labw[g] = *(const unsigned*)&lab[mb + hi * 4 + g * 8];
#pragma unroll
            for (int r = 0; r < 16; ++r) {
                float e = __expf(s[r] * SCALE);
                p[r] = (((labw[r >> 2] >> (8 * (r & 3))) & 255u) == lr) ? e : 0.0f;
            }
        }
#pragma unroll
        for (int r = 0; r < 16; ++r) psum += p[r];
        unsigned pk0, pk1, pk2, pk3, pk4, pk5, pk6, pk7;
        asm("v_cvt_pk_bf16_f32 %0, %1, %2" : "=v"(pk0) : "v"(p[0]),  "v"(p[1]));
        asm("v_cvt_pk_bf16_f32 %0, %1, %2" : "=v"(pk1) : "v"(p[2]),  "v"(p[3]));
        asm("v_cvt_pk_bf16_f32 %0, %1, %2" : "=v"(pk2) : "v"(p[4]),  "v"(p[5]));
        asm("v_cvt_pk_bf16_f32 %0, %1, %2" : "=v"(pk3) : "v"(p[6]),  "v"(p[7]));
        asm("v_cvt_pk_bf16_f32 %0, %1, %2" : "=v"(pk4) : "v"(p[8]),  "v"(p[9]));
        asm("v_cvt_pk_bf16_f32 %0, %1, %2" : "=v"(pk5) : "v"(p[10]), "v"(p[11]));
        asm("v_cvt_pk_bf16_f32 %0, %1, %2" : "=v"(pk6) : "v"(p[12]), "v"(p[13]));
        asm("v_cvt_pk_bf16_f32 %0, %1, %2" : "=v"(pk7) : "v"(p[14]), "v"(p[15]));
        asm volatile("v_permlane32_swap_b32 %0, %1" : "+v"(pk0), "+v"(pk2));
        asm volatile("v_permlane32_swap_b32 %0, %1" : "+v"(pk1), "+v"(pk3));
        asm volatile("v_permlane32_swap_b32 %0, %1" : "+v"(pk4), "+v"(pk6));
        asm volatile("v_permlane32_swap_b32 %0, %1" : "+v"(pk5), "+v"(pk7));
        u32x4 A1 = {pk0, pk1, pk2, pk3};
        u32x4 A2 = {pk4, pk5, pk6, pk7};
        bf16x8 pa0 = __builtin_bit_cast(bf16x8, A1);
        bf16x8 pa1 = __builtin_bit_cast(bf16x8, A2);
        const u16* vp = &Vt[l31 * 360 + mb + hi * 8];
        bf16x8 vb0 = *(const bf16x8*)vp;
        bf16x8 vb1 = *(const bf16x8*)(vp + 16);
        o = __builtin_amdgcn_mfma_f32_32x32x16_bf16(pa0, vb0, o, 0, 0, 0);
        o = __builtin_amdgcn_mfma_f32_32x32x16_bf16(pa1, vb1, o, 0, 0, 0);
    };

    if (uni) {
#pragma unroll 2
        for (int c = 0; c < 10; ++c) chunk(c, 0);
        chunk(10, 1);
    } else {
#pragma unroll 2
        for (int c = 0; c < 11; ++c) chunk(c, 2);
    }

    psum += __shfl_xor(psum, 32);
    float inv = 1.0f / psum;
#pragma unroll
    for (int r = 0; r < 16; ++r) {
        int crow = (r & 3) + 8 * (r >> 2) + 4 * hi;
        int n = n0 + crow;
        float invc = __shfl(inv, crow);            // inv uniform across halves
        if (n < 343) {
            u16* op = o_win + (base + n) * 192 + head * 32;
            op[l31] = f2us(o[r] * invc);
        }
    }
}

// ---------------------------------------------------------------------------
extern "C" void kernel_launch(void* const* d_in, const int* in_sizes, int n_in,
                              void* d_out, int out_size, void* d_ws, size_t ws_size,
                              hipStream_t stream)
{
    const float* x      = (const float*)d_in[0];
    const float* ln1_g  = (const float*)d_in[1];
    const float* ln1_b  = (const float*)d_in[2];
    const float* qkv_w  = (const float*)d_in[3];
    const float* qkv_b  = (const float*)d_in[4];
    const float* rpb    = (const float*)d_in[5];
    const float* proj_w = (const float*)d_in[6];
    const float* proj_b = (const float*)d_in[7];
    const float* ln2_g  = (const float*)d_in[8];
    const float* ln2_b  = (const float*)d_in[9];
    const float* fc1_w  = (const float*)d_in[10];
    const float* fc1_b  = (const float*)d_in[11];
    const float* fc2_w  = (const float*)d_in[12];
    const float* fc2_b  = (const float*)d_in[13];

    const int M = 43904;                   // tokens = B*nW*N (343 x 128-row tiles)
    const size_t MC  = (size_t)M * 192;
    const size_t MC2 = MC * 2;             // bytes of a bf16 [M,192] buffer

    char* ws = (char*)d_ws;
    u16* hA     = (u16*)ws;
    u16* qkvb   = (u16*)(ws + MC2);
    u16* projw  = (u16*)(ws + MC2);
    u16* gbuf   = (u16*)(ws + MC2);
    u16* fc1_wb = (u16*)(ws + 51u * 1024 * 1024);
    u16* fc2_wb = (u16*)(ws + 51u * 1024 * 1024 + 294912);
    float* out  = (float*)d_out;
    u16* qkv_wb  = (u16*)d_out;            // 110592 u16
    u16* proj_wb = (u16*)d_out + 110592;   //  36864 u16
    float* biasF = (float*)((char*)d_out + 4u * 1024 * 1024);  // 743424 f32 = 2.97MB

    // Phase 1: prep (weights->bf16 + fragment-ordered bias), LN1, QKV, attention
    k_prep<<<3481, 256, 0, stream>>>(qkv_w, proj_w, rpb, qkv_wb, proj_wb, biasF);
    k_ln1_winpart<<<M / 4, 256, 0, stream>>>(x, ln1_g, ln1_b, hA);
    k_gemm32<0, 1, 9><<<3087, 256, 0, stream>>>(hA, qkv_wb, qkv_b, qkvb, nullptr, nullptr, M, 576, 192);
    k_attn<<<dim3(6, 64, 2), 704, 0, stream>>>(qkvb, biasF, hA);
    // fc weights into dead qkvb tail (must be after attn)
    k_f2b2<<<1152, 256, 0, stream>>>(fc1_w, fc2_w, fc1_wb, fc2_wb);
    // proj (MFMA), fused window-reverse + residual + LN2
    k_gemm32<0, 1, 3><<<1029, 256, 0, stream>>>(hA, proj_wb, proj_b, projw, nullptr, nullptr, M, 192, 192);
    k_add_winrev_ln2<<<M / 4, 256, 0, stream>>>(x, projw, ln2_g, ln2_b, out, hA);
    // Phase 2: MLP, 2 chunks (172 + 171 row-tiles); fc1 BK=32, fc2 BK=64
    const int CH0 = 22016, CH1 = 21888;
    k_gemm32<1, 1, 12><<<2064, 256, 0, stream>>>(hA, fc1_wb, fc1_b, gbuf, nullptr, nullptr, CH0, 768, 192);
    k_gemm_mfma<0, 2, 3><<<516, 256, 0, stream>>>(gbuf, fc2_wb, fc2_b, nullptr, out, out, CH0, 192, 768);
    k_gemm32<1, 1, 12><<<2052, 256, 0, stream>>>(hA + (size_t)CH0 * 192, fc1_wb, fc1_b, gbuf, nullptr, nullptr, CH1, 768, 192);
    k_gemm_mfma<0, 2, 3><<<513, 256, 0, stream>>>(gbuf, fc2_wb, fc2_b, nullptr, out + (size_t)CH0 * 192, out + (size_t)CH0 * 192, CH1, 192, 768);
}

// Round 16
// 280.097 us; speedup vs baseline: 1.0262x; 1.0262x over previous
//
#include <hip/hip_runtime.h>
#include <hip/hip_bf16.h>
#include <math.h>

typedef __hip_bfloat16 bf16;
typedef unsigned short u16;
typedef __attribute__((ext_vector_type(8))) short bf16x8;
typedef __attribute__((ext_vector_type(4))) float f32x4;
typedef __attribute__((ext_vector_type(16))) float f32x16;
typedef __attribute__((ext_vector_type(4))) unsigned u32x4;

__device__ __forceinline__ float us2f(u16 u) { return __uint_as_float(((unsigned)u) << 16); }
__device__ __forceinline__ u16 f2us(float f) { bf16 h = __float2bfloat16(f); return *(u16*)&h; }

__device__ __forceinline__ float wave_bcast_sum(float v) {
#pragma unroll
    for (int off = 32; off > 0; off >>= 1) v += __shfl_down(v, off);
    return __shfl(v, 0);
}

// async global->LDS, 16B per lane. LDS dest is wave-uniform base (+lane*16 by HW).
__device__ __forceinline__ void glds16(const u16* g, u16* l) {
    __builtin_amdgcn_global_load_lds((const __attribute__((address_space(1))) void*)g,
                                     (__attribute__((address_space(3))) void*)l, 16, 0, 0);
}

// ---------------------------------------------------------------------------
// Merged LN1+winpart AND prep (weights->bf16 + fragment-ordered bias table).
// Blocks [0, 10976): LN1 + roll(-3) + window partition (one wave per token).
// Blocks [10976, 14457): qkv_w/proj_w -> bf16, biasF table.
// biasF[((h*11+tile)*11+chunk)*1024 + lane*16 + g*4 + q] = rpb[relidx]/scale,
// n = tile*32 + (lane&31), m = chunk*32 + 4*(lane>>5) + 8*g + q; pads = 0.
// ---------------------------------------------------------------------------
__global__ __launch_bounds__(256) void k_ln1_prep(
    const float* __restrict__ x, const float* __restrict__ g, const float* __restrict__ b,
    u16* __restrict__ out,
    const float* __restrict__ qkv_w, const float* __restrict__ proj_w,
    const float* __restrict__ rpb,
    u16* __restrict__ qkv_wb, u16* __restrict__ proj_wb, float* __restrict__ biasF)
{
    if (blockIdx.x >= 10976) {
        int idx = (blockIdx.x - 10976) * 256 + threadIdx.x;
        if (idx < 110592) { qkv_wb[idx] = f2us(qkv_w[idx]); return; }
        idx -= 110592;
        if (idx < 36864) { proj_wb[idx] = f2us(proj_w[idx]); return; }
        idx -= 36864;
        if (idx >= 6 * 11 * 11 * 1024) return;
        int r16 = idx & 15;                    // g*4 + q
        int lane = (idx >> 4) & 63;
        int cell = idx >> 10;                  // (h*11 + tile)*11 + chunk
        int chunk = cell % 11;
        int t2 = cell / 11;
        int tile = t2 % 11;
        int h = t2 / 11;
        int gg = r16 >> 2, q = r16 & 3;
        int hi = lane >> 5, l31 = lane & 31;
        int n = tile * 32 + l31;
        int m = chunk * 32 + 4 * hi + 8 * gg + q;
        float v = 0.0f;
        if (m < 343 && n < 343) {
            int ni = n / 49, nr = n - ni * 49, nj = nr / 7, nk = nr - nj * 7;
            int mi = m / 49, mr = m - mi * 49, mj = mr / 7, mk = mr - mj * 7;
            int d = (ni - mi) * 169 + (nj - mj) * 13 + (nk - mk) + 1098;
            v = rpb[d * 6 + h] * 5.656854249492381f;   // * sqrt(32) = / scale
        }
        biasF[idx] = v;
        return;
    }
    int lane = threadIdx.x & 63;
    int t = blockIdx.x * 4 + (threadIdx.x >> 6);
    int bidx = t / (64 * 343);
    int r = t - bidx * (64 * 343);
    int w = r / 343;
    int n = r - w * 343;
    int wd = w >> 4, wh = (w >> 2) & 3, ww = w & 3;
    int i = n / 49, rem = n - i * 49;
    int j = rem / 7, k = rem - j * 7;
    int sd = wd * 7 + i + 3; if (sd >= 28) sd -= 28;
    int sh = wh * 7 + j + 3; if (sh >= 28) sh -= 28;
    int sw = ww * 7 + k + 3; if (sw >= 28) sw -= 28;
    size_t src = ((((size_t)bidx * 28 + sd) * 28 + sh) * 28 + sw) * 192;
    float v0 = x[src + lane], v1 = x[src + lane + 64], v2 = x[src + lane + 128];
    float s  = wave_bcast_sum(v0 + v1 + v2);
    float mu = s * (1.0f / 192.0f);
    float s2 = wave_bcast_sum(v0 * v0 + v1 * v1 + v2 * v2);
    float rs = rsqrtf(s2 * (1.0f / 192.0f) - mu * mu + 1e-5f);
    u16* op = out + (size_t)t * 192;
    op[lane]       = f2us((v0 - mu) * rs * g[lane]       + b[lane]);
    op[lane + 64]  = f2us((v1 - mu) * rs * g[lane + 64]  + b[lane + 64]);
    op[lane + 128] = f2us((v2 - mu) * rs * g[lane + 128] + b[lane + 128]);
}

// fc1_w + fc2_w -> bf16 (must run after attn frees the qkvb tail)
__global__ __launch_bounds__(256) void k_f2b2(
    const float* __restrict__ fc1_w, const float* __restrict__ fc2_w,
    u16* __restrict__ fc1_wb, u16* __restrict__ fc2_wb)
{
    int idx = blockIdx.x * 256 + threadIdx.x;
    if (idx < 147456) fc1_wb[idx] = f2us(fc1_w[idx]);
    else fc2_wb[idx - 147456] = f2us(fc2_w[idx - 147456]);
}

// ---------------------------------------------------------------------------
// Fused: window reverse + roll(+3) + residual add (f32 x1 out) + LN2 (bf16 out)
// ---------------------------------------------------------------------------
__global__ __launch_bounds__(256) void k_add_winrev_ln2(
    const float* __restrict__ x, const u16* __restrict__ projw,
    const float* __restrict__ g, const float* __restrict__ b,
    float* __restrict__ x1, u16* __restrict__ h2)
{
    int lane = threadIdx.x & 63;
    int t = blockIdx.x * 4 + (threadIdx.x >> 6);
    int sw_ = t % 28, t1 = t / 28;
    int sh_ = t1 % 28, t2 = t1 / 28;
    int sd_ = t2 % 28, bidx = t2 / 28;
    int rd = sd_ + 25; if (rd >= 28) rd -= 28;   // (d-3) mod 28
    int rh = sh_ + 25; if (rh >= 28) rh -= 28;
    int rw = sw_ + 25; if (rw >= 28) rw -= 28;
    int wd = rd / 7, i = rd - wd * 7;
    int wh = rh / 7, j = rh - wh * 7;
    int ww = rw / 7, k = rw - ww * 7;
    int w = (wd << 4) + (wh << 2) + ww;
    int n = (i * 7 + j) * 7 + k;
    size_t src = (((size_t)(bidx * 64 + w)) * 343 + n) * 192;
    const float* xp = x + (size_t)t * 192;
    float v0 = xp[lane]       + us2f(projw[src + lane]);
    float v1 = xp[lane + 64]  + us2f(projw[src + lane + 64]);
    float v2 = xp[lane + 128] + us2f(projw[src + lane + 128]);
    float* op = x1 + (size_t)t * 192;
    op[lane] = v0; op[lane + 64] = v1; op[lane + 128] = v2;
    float s  = wave_bcast_sum(v0 + v1 + v2);
    float mu = s * (1.0f / 192.0f);
    float s2 = wave_bcast_sum(v0 * v0 + v1 * v1 + v2 * v2);
    float rs = rsqrtf(s2 * (1.0f / 192.0f) - mu * mu + 1e-5f);
    u16* hp = h2 + (size_t)t * 192;
    hp[lane]       = f2us((v0 - mu) * rs * g[lane]       + b[lane]);
    hp[lane + 64]  = f2us((v1 - mu) * rs * g[lane + 64]  + b[lane + 64]);
    hp[lane + 128] = f2us((v2 - mu) * rs * g[lane + 128] + b[lane + 128]);
}

// ---------------------------------------------------------------------------
// MFMA GEMM, BK=64 double-buffered 2-phase, XOR-swizzled LDS.
// 1D grid + XCD-aware bijective block swizzle (m204), y-major logical order.
// out[m,n] = epi( sum_k A[m,k]*W[n,k] + bias[n] ). BM=128, BN=64.
// K % 64 == 0. ACT: 0 none, 1 gelu. OUT: 1 bf16, 2 f32 + resid add.
// ---------------------------------------------------------------------------
template<int ACT, int OUT, int GX>
__global__ __launch_bounds__(256) void k_gemm_mfma(
    const u16* __restrict__ A, const u16* __restrict__ W, const float* __restrict__ bias,
    u16* __restrict__ outB, float* __restrict__ outF, const float* __restrict__ resid,
    int M, int Nc, int K)
{
    __shared__ __align__(16) u16 As[2][128 * 64];
    __shared__ __align__(16) u16 Bs[2][64 * 64];
    int tid = threadIdx.x;
    int lane = tid & 63, wv = tid >> 6;
    int quad = lane >> 4, l16 = lane & 15;

    int nwg = gridDim.x, orig = blockIdx.x;
    int q = nwg >> 3, r = nwg & 7;
    int xcd = orig & 7, lin = orig >> 3;
    int L = (xcd < r ? xcd * (q + 1) : r * (q + 1) + (xcd - r) * q) + lin;
    int bx = L % GX, by = L / GX;
    int m0 = by << 7, n0 = bx << 6;

    f32x4 acc[2][4] = {};

    int srow = wv * 8 + (lane >> 3);              // row for i=0
    int swz  = ((lane & 7) << 3) ^ (((lane >> 3) & 7) << 3);
    const u16* gA = A + (size_t)(m0 + srow) * K + swz;
    const u16* gB = W + (size_t)(n0 + srow) * K + swz;
    int rsA = 32 * K;                             // row step per iter (i*32 rows)

    int nst = K >> 6;
#define STAGE(buf, k0)                                                        \
    {                                                                         \
        _Pragma("unroll")                                                     \
        for (int i = 0; i < 4; i++)                                           \
            glds16(gA + (size_t)i * rsA + (k0), &As[buf][(i * 4 + wv) * 512]); \
        _Pragma("unroll")                                                     \
        for (int i = 0; i < 2; i++)                                           \
            glds16(gB + (size_t)i * rsA + (k0), &Bs[buf][(i * 4 + wv) * 512]); \
    }

    STAGE(0, 0);
    asm volatile("s_waitcnt vmcnt(0)" ::: "memory");
    __builtin_amdgcn_s_barrier();

    int rswz = (l16 & 7) << 3;                    // read-side swizzle (row&7 == l16&7)
    int cur = 0;
    for (int t = 0; t < nst; ++t) {
        if (t + 1 < nst) STAGE(cur ^ 1, (t + 1) << 6);
#pragma unroll
        for (int kk = 0; kk < 2; kk++) {
            int ko = (kk * 32 + quad * 8) ^ rswz;
            bf16x8 af[2], bfr[4];
#pragma unroll
            for (int mt = 0; mt < 2; mt++)
                af[mt] = *(const bf16x8*)&As[cur][(wv * 32 + mt * 16 + l16) * 64 + ko];
#pragma unroll
            for (int nt = 0; nt < 4; nt++)
                bfr[nt] = *(const bf16x8*)&Bs[cur][(nt * 16 + l16) * 64 + ko];
#pragma unroll
            for (int mt = 0; mt < 2; mt++)
#pragma unroll
                for (int nt = 0; nt < 4; nt++)
                    acc[mt][nt] = __builtin_amdgcn_mfma_f32_16x16x32_bf16(af[mt], bfr[nt], acc[mt][nt], 0, 0, 0);
        }
        asm volatile("s_waitcnt vmcnt(0)" ::: "memory");
        __builtin_amdgcn_s_barrier();
        cur ^= 1;
    }
#undef STAGE
#pragma unroll
    for (int mt = 0; mt < 2; mt++) {
#pragma unroll
        for (int nt = 0; nt < 4; nt++) {
#pragma unroll
            for (int r2 = 0; r2 < 4; r2++) {
                int m = m0 + wv * 32 + mt * 16 + quad * 4 + r2;
                int n = n0 + nt * 16 + l16;
                float v = acc[mt][nt][r2] + bias[n];
                if (ACT == 1) v = 0.5f * v * (1.0f + erff(v * 0.70710678118654752f));
                size_t off = (size_t)m * Nc + n;
                if (OUT == 1) outB[off] = f2us(v);
                else outF[off] = resid[off] + v;
            }
        }
    }
}

// ---------------------------------------------------------------------------
// Fused windowed attention (R8-proven): 32x32x16 MFMA, swapped QK^T,
// fragment-ordered bias C-in. 11 waves (704 thr), one query-tile per wave.
// ---------------------------------------------------------------------------
__global__ __launch_bounds__(704, 6) void k_attn(
    const u16* __restrict__ qkv, const float* __restrict__ biasF, u16* __restrict__ o_win)
{
    int head = blockIdx.x;
    int w = blockIdx.y;
    int bidx = blockIdx.z;
    __shared__ __align__(16) u16 Ks[352 * 40];
    __shared__ __align__(16) u16 Vt[32 * 360];
    __shared__ unsigned char lab[352];
    int tid = threadIdx.x;
    int lane = tid & 63, wv = tid >> 6;        // wv 0..10
    int hi = lane >> 5, l31 = lane & 31;
    size_t base = ((size_t)(bidx * 64 + w)) * 343;

    for (int i = tid; i < 2816; i += 704) {
        int m = i >> 3;
        int d4 = (i & 7) << 2;
        ushort4 kv = {0, 0, 0, 0}, vv = {0, 0, 0, 0};
        if (m < 343) {
            size_t off = (base + m) * 576 + head * 32 + d4;
            kv = *(const ushort4*)(qkv + off + 192);
            vv = *(const ushort4*)(qkv + off + 384);
        }
        *(ushort4*)&Ks[m * 40 + d4] = kv;
        Vt[(d4 + 0) * 360 + m] = vv.x;
        Vt[(d4 + 1) * 360 + m] = vv.y;
        Vt[(d4 + 2) * 360 + m] = vv.z;
        Vt[(d4 + 3) * 360 + m] = vv.w;
    }
    int wd = w >> 4, wh = (w >> 2) & 3, ww = w & 3;
    bool uni = (wd < 3) && (wh < 3) && (ww < 3);
    for (int n = tid; n < 352; n += 704) {
        unsigned char lv = 255;                      // pad rows never match
        if (n < 343) {
            int i = n / 49, rem = n - i * 49;
            int j = rem / 7, k = rem - j * 7;
            int gd = wd * 7 + i, gh = wh * 7 + j, gw = ww * 7 + k;
            int ld_ = (gd < 21) ? 0 : ((gd < 25) ? 1 : 2);
            int lh_ = (gh < 21) ? 0 : ((gh < 25) ? 1 : 2);
            int lw_ = (gw < 21) ? 0 : ((gw < 25) ? 1 : 2);
            lv = (unsigned char)(ld_ * 9 + lh_ * 3 + lw_);
        }
        lab[n] = lv;
    }
    __syncthreads();

    const float SCALE = 0.17677669529663687f;  // 1/sqrt(32)
    const f32x16 z16 = {0,0,0,0,0,0,0,0,0,0,0,0,0,0,0,0};

    int tile = wv;                              // one tile per wave, 0..10
    int n0 = tile * 32;
    int nq = n0 + l31; if (nq > 342) nq = 342;
    const u16* qp = qkv + (base + nq) * 576 + head * 32;
    bf16x8 bq0 = *(const bf16x8*)(qp + hi * 8);        // Q[n=l31][d=hi*8+j]
    bf16x8 bq1 = *(const bf16x8*)(qp + 16 + hi * 8);   // d=16+hi*8+j
    unsigned lr = lab[n0 + l31];
    const float* bfr = biasF + ((size_t)(head * 11 + tile) * 11) * 1024 + lane * 16;

    f32x16 o = z16;
    float psum = 0.0f;

    // mode: 0 = no mask, 1 = pad-kill only, 2 = full label mask
    auto chunk = [&](int c, int mode) {
        int mb = c * 32;
        const u16* kp = &Ks[(mb + l31) * 40 + hi * 8];
        bf16x8 ka0 = *(const bf16x8*)kp;
        bf16x8 ka1 = *(const bf16x8*)(kp + 16);
        f32x16 s;
        const float* bc = bfr + c * 1024;
#pragma unroll
        for (int g = 0; g < 4; ++g)
            ((float4*)&s)[g] = *(const float4*)(bc + g * 4);
        s = __builtin_amdgcn_mfma_f32_32x32x16_bf16(ka0, bq0, s, 0, 0, 0);
        s = __builtin_amdgcn_mfma_f32_32x32x16_bf16(ka1, bq1, s, 0, 0, 0);
        float p[16];
        if (mode == 0) {
#pragma unroll
            for (int r = 0; r < 16; ++r) p[r] = __expf(s[r] * SCALE);
        } else if (mode == 1) {
#pragma unroll
            for (int r = 0; r < 16; ++r) {
                int m = mb + 4 * hi + 8 * (r >> 2) + (r & 3);
                float e = __expf(s[r] * SCALE);
                p[r] = (m < 343) ? e : 0.0f;
            }
        } else {
            unsigned labw[4];
#pragma unroll
            for (int g = 0; g < 4; ++g)
                labw[g] = *(const unsigned*)&lab[mb + hi * 4 + g * 8];
#pragma unroll
            for (int r = 0; r < 16; ++r) {
                float e = __expf(s[r] * SCALE);
                p[r] = (((labw[r >> 2] >> (8 * (r & 3))) & 255u) == lr) ? e : 0.0f;
            }
        }
#pragma unroll
        for (int r = 0; r < 16; ++r) psum += p[r];
        unsigned pk0, pk1, pk2, pk3, pk4, pk5, pk6, pk7;
        asm("v_cvt_pk_bf16_f32 %0, %1, %2" : "=v"(pk0) : "v"(p[0]),  "v"(p[1]));
        asm("v_cvt_pk_bf16_f32 %0, %1, %2" : "=v"(pk1) : "v"(p[2]),  "v"(p[3]));
        asm("v_cvt_pk_bf16_f32 %0, %1, %2" : "=v"(pk2) : "v"(p[4]),  "v"(p[5]));
        asm("v_cvt_pk_bf16_f32 %0, %1, %2" : "=v"(pk3) : "v"(p[6]),  "v"(p[7]));
        asm("v_cvt_pk_bf16_f32 %0, %1, %2" : "=v"(pk4) : "v"(p[8]),  "v"(p[9]));
        asm("v_cvt_pk_bf16_f32 %0, %1, %2" : "=v"(pk5) : "v"(p[10]), "v"(p[11]));
        asm("v_cvt_pk_bf16_f32 %0, %1, %2" : "=v"(pk6) : "v"(p[12]), "v"(p[13]));
        asm("v_cvt_pk_bf16_f32 %0, %1, %2" : "=v"(pk7) : "v"(p[14]), "v"(p[15]));
        asm volatile("v_permlane32_swap_b32 %0, %1" : "+v"(pk0), "+v"(pk2));
        asm volatile("v_permlane32_swap_b32 %0, %1" : "+v"(pk1), "+v"(pk3));
        asm volatile("v_permlane32_swap_b32 %0, %1" : "+v"(pk4), "+v"(pk6));
        asm volatile("v_permlane32_swap_b32 %0, %1" : "+v"(pk5), "+v"(pk7));
        u32x4 A1 = {pk0, pk1, pk2, pk3};
        u32x4 A2 = {pk4, pk5, pk6, pk7};
        bf16x8 pa0 = __builtin_bit_cast(bf16x8, A1);
        bf16x8 pa1 = __builtin_bit_cast(bf16x8, A2);
        const u16* vp = &Vt[l31 * 360 + mb + hi * 8];
        bf16x8 vb0 = *(const bf16x8*)vp;
        bf16x8 vb1 = *(const bf16x8*)(vp + 16);
        o = __builtin_amdgcn_mfma_f32_32x32x16_bf16(pa0, vb0, o, 0, 0, 0);
        o = __builtin_amdgcn_mfma_f32_32x32x16_bf16(pa1, vb1, o, 0, 0, 0);
    };

    if (uni) {
#pragma unroll 2
        for (int c = 0; c < 10; ++c) chunk(c, 0);
        chunk(10, 1);
    } else {
#pragma unroll 2
        for (int c = 0; c < 11; ++c) chunk(c, 2);
    }

    psum += __shfl_xor(psum, 32);
    float inv = 1.0f / psum;
#pragma unroll
    for (int r = 0; r < 16; ++r) {
        int crow = (r & 3) + 8 * (r >> 2) + 4 * hi;
        int n = n0 + crow;
        float invc = __shfl(inv, crow);            // inv uniform across halves
        if (n < 343) {
            u16* op = o_win + (base + n) * 192 + head * 32;
            op[l31] = f2us(o[r] * invc);
        }
    }
}

// ---------------------------------------------------------------------------
extern "C" void kernel_launch(void* const* d_in, const int* in_sizes, int n_in,
                              void* d_out, int out_size, void* d_ws, size_t ws_size,
                              hipStream_t stream)
{
    const float* x      = (const float*)d_in[0];
    const float* ln1_g  = (const float*)d_in[1];
    const float* ln1_b  = (const float*)d_in[2];
    const float* qkv_w  = (const float*)d_in[3];
    const float* qkv_b  = (const float*)d_in[4];
    const float* rpb    = (const float*)d_in[5];
    const float* proj_w = (const float*)d_in[6];
    const float* proj_b = (const float*)d_in[7];
    const float* ln2_g  = (const float*)d_in[8];
    const float* ln2_b  = (const float*)d_in[9];
    const float* fc1_w  = (const float*)d_in[10];
    const float* fc1_b  = (const float*)d_in[11];
    const float* fc2_w  = (const float*)d_in[12];
    const float* fc2_b  = (const float*)d_in[13];

    const int M = 43904;                   // tokens = B*nW*N (343 x 128-row tiles)
    const size_t MC  = (size_t)M * 192;
    const size_t MC2 = MC * 2;             // bytes of a bf16 [M,192] buffer

    char* ws = (char*)d_ws;
    u16* hA     = (u16*)ws;
    u16* qkvb   = (u16*)(ws + MC2);
    u16* projw  = (u16*)(ws + MC2);
    u16* gbuf   = (u16*)(ws + MC2);
    u16* fc1_wb = (u16*)(ws + 51u * 1024 * 1024);
    u16* fc2_wb = (u16*)(ws + 51u * 1024 * 1024 + 294912);
    float* out  = (float*)d_out;
    u16* qkv_wb  = (u16*)d_out;            // 110592 u16
    u16* proj_wb = (u16*)d_out + 110592;   //  36864 u16
    float* biasF = (float*)((char*)d_out + 4u * 1024 * 1024);  // 743424 f32 = 2.97MB

    // Phase 1: merged LN1+prep, QKV (MFMA), attention
    k_ln1_prep<<<14457, 256, 0, stream>>>(x, ln1_g, ln1_b, hA, qkv_w, proj_w, rpb, qkv_wb, proj_wb, biasF);
    k_gemm_mfma<0, 1, 9><<<3087, 256, 0, stream>>>(hA, qkv_wb, qkv_b, qkvb, nullptr, nullptr, M, 576, 192);
    k_attn<<<dim3(6, 64, 2), 704, 0, stream>>>(qkvb, biasF, hA);
    // fc weights into dead qkvb tail (must be after attn)
    k_f2b2<<<1152, 256, 0, stream>>>(fc1_w, fc2_w, fc1_wb, fc2_wb);
    // proj (MFMA), fused window-reverse + residual + LN2
    k_gemm_mfma<0, 1, 3><<<1029, 256, 0, stream>>>(hA, proj_wb, proj_b, projw, nullptr, nullptr, M, 192, 192);
    k_add_winrev_ln2<<<M / 4, 256, 0, stream>>>(x, projw, ln2_g, ln2_b, out, hA);
    // Phase 2: MLP (MFMA), 2 chunks (172 + 171 row-tiles)
    const int CH0 = 22016, CH1 = 21888;
    k_gemm_mfma<1, 1, 12><<<2064, 256, 0, stream>>>(hA, fc1_wb, fc1_b, gbuf, nullptr, nullptr, CH0, 768, 192);
    k_gemm_mfma<0, 2, 3><<<516, 256, 0, stream>>>(gbuf, fc2_wb, fc2_b, nullptr, out, out, CH0, 192, 768);
    k_gemm_mfma<1, 1, 12><<<2052, 256, 0, stream>>>(hA + (size_t)CH0 * 192, fc1_wb, fc1_b, gbuf, nullptr, nullptr, CH1, 768, 192);
    k_gemm_mfma<0, 2, 3><<<513, 256, 0, stream>>>(gbuf, fc2_wb, fc2_b, nullptr, out + (size_t)CH0 * 192, out + (size_t)CH0 * 192, CH1, 192, 768);
}